// Round 1
// 437.995 us; speedup vs baseline: 1.1672x; 1.1672x over previous
//
#include <hip/hip_runtime.h>
#include <hip/hip_bf16.h>

constexpr int N_NODES = 150000;
constexpr int N_EDGES = 2400000;
constexpr int D       = 128;
constexpr float LEAKY = 0.2f;
constexpr float L2EPS = 1e-12f;

constexpr int NB_SCAN = (N_NODES + 255) / 256;   // 586 (<1024)

// Bucket sort params
constexpr int RB_LOG = 9;                               // 512 rows / bucket
constexpr int RB     = 1 << RB_LOG;
constexpr int NBK    = (N_NODES + RB - 1) >> RB_LOG;    // 293
constexpr int EPT_A  = 32;                              // edges / thread, phase A
constexpr int EPB_A  = 256 * EPT_A;                     // 8192 edges / block

typedef short  short8  __attribute__((ext_vector_type(8)));
typedef short  short4v __attribute__((ext_vector_type(4)));
typedef float  f32x4   __attribute__((ext_vector_type(4)));

static __device__ __forceinline__ short f2bf(float x) {
  __hip_bfloat16 h = __float2bfloat16(x);
  return *reinterpret_cast<short*>(&h);
}

// ===========================================================================
// NEW: bucket-level histogram (LDS-aggregated -> 293 global atomics / block)
// Replaces the per-row hist_kernel whose 2.4M device-scope atomics generated
// 75 MB of memory-side write traffic (96 us).
// ===========================================================================
__global__ __launch_bounds__(256) void bucket_hist_kernel(
    const int* __restrict__ erow, int* __restrict__ bkt_cnt) {
  __shared__ int h[NBK];
  const int t = threadIdx.x;
  for (int i = t; i < NBK; i += 256) h[i] = 0;
  __syncthreads();
  const long long e0 = (long long)blockIdx.x * EPB_A;
  #pragma unroll
  for (int k = 0; k < EPT_A; ++k) {
    long long e = e0 + k * 256 + t;
    if (e < N_EDGES) atomicAdd(&h[erow[e] >> RB_LOG], 1);
  }
  __syncthreads();
  for (int i = t; i < NBK; i += 256) {
    int c = h[i];
    if (c) atomicAdd(&bkt_cnt[i], c);
  }
}

// Single-block exclusive scan over the 293 bucket counts.
__global__ __launch_bounds__(512) void bucket_scan_kernel(
    const int* __restrict__ bkt_cnt,
    int* __restrict__ bbase,        // NBK+1 entries
    int* __restrict__ bcur,
    int* __restrict__ offs) {
  __shared__ int s[512];
  const int t = threadIdx.x;
  int v = (t < NBK) ? bkt_cnt[t] : 0;
  s[t] = v;
  __syncthreads();
  for (int off = 1; off < 512; off <<= 1) {
    int tmp = (t >= off) ? s[t - off] : 0;
    __syncthreads();
    s[t] += tmp;
    __syncthreads();
  }
  if (t < NBK) {
    int excl = s[t] - v;
    bbase[t] = excl;
    bcur[t]  = excl;
  }
  if (t == 0) { bbase[NBK] = N_EDGES; offs[N_NODES] = N_EDGES; }
}

// ===========================================================================
// Old per-row histogram + scans (kept for the mid-tier bin fallback only)
// ===========================================================================
__global__ __launch_bounds__(256) void hist_kernel(
    const int* __restrict__ erow, int* __restrict__ cnt) {
  int base = blockIdx.x * 2048 + threadIdx.x;
  #pragma unroll
  for (int k = 0; k < 8; ++k) {
    int e = base + k * 256;
    if (e < N_EDGES) atomicAdd(&cnt[erow[e]], 1);
  }
}

__global__ __launch_bounds__(256) void scan_block_sums(
    const int* __restrict__ cnt, int* __restrict__ bsums) {
  __shared__ int s[256];
  int i = blockIdx.x * 256 + threadIdx.x;
  s[threadIdx.x] = (i < N_NODES) ? cnt[i] : 0;
  __syncthreads();
  for (int off = 128; off > 0; off >>= 1) {
    if (threadIdx.x < off) s[threadIdx.x] += s[threadIdx.x + off];
    __syncthreads();
  }
  if (threadIdx.x == 0) bsums[blockIdx.x] = s[0];
}

__global__ __launch_bounds__(1024) void scan_partials(int* __restrict__ bsums) {
  __shared__ int s[1024];
  int v = (threadIdx.x < NB_SCAN) ? bsums[threadIdx.x] : 0;
  s[threadIdx.x] = v;
  __syncthreads();
  for (int off = 1; off < 1024; off <<= 1) {
    int t = (threadIdx.x >= off) ? s[threadIdx.x - off] : 0;
    __syncthreads();
    s[threadIdx.x] += t;
    __syncthreads();
  }
  if (threadIdx.x < NB_SCAN) bsums[threadIdx.x] = s[threadIdx.x] - v;  // exclusive
}

__global__ __launch_bounds__(256) void scan_final(
    const int* __restrict__ cnt, const int* __restrict__ bsums,
    int* __restrict__ offs, int* __restrict__ cursor) {
  __shared__ int s[256];
  int i = blockIdx.x * 256 + threadIdx.x;
  int v = (i < N_NODES) ? cnt[i] : 0;
  s[threadIdx.x] = v;
  __syncthreads();
  for (int off = 1; off < 256; off <<= 1) {
    int t = (threadIdx.x >= off) ? s[threadIdx.x - off] : 0;
    __syncthreads();
    s[threadIdx.x] += t;
    __syncthreads();
  }
  if (i < N_NODES) {
    int excl = s[threadIdx.x] - v + bsums[blockIdx.x];
    offs[i]   = excl;
    cursor[i] = excl;
  }
  if (i == 0) offs[N_NODES] = N_EDGES;
}

// ===========================================================================
// Phase A: bucket scatter with coalesced run-writes into stage.
// stage layout == final layout at bucket granularity (base = bbase[bkt]).
// Packs rlocal (9 bits) into bits 18..26 of the col word.
// ===========================================================================
__global__ __launch_bounds__(256) void bucket_scatter_kernel(
    const int*   __restrict__ erow,
    const int*   __restrict__ ecol,
    const float* __restrict__ eval,
    int*         __restrict__ bcur,
    int2*        __restrict__ stage) {
  __shared__ int h[NBK];
  __shared__ int basea[NBK];
  const int t = threadIdx.x;
  const long long e0 = (long long)blockIdx.x * EPB_A;

  for (int i = t; i < NBK; i += 256) h[i] = 0;
  __syncthreads();

  int rows[EPT_A];
  #pragma unroll
  for (int k = 0; k < EPT_A; ++k) {
    long long e = e0 + k * 256 + t;
    int r = -1;
    if (e < N_EDGES) { r = erow[e]; atomicAdd(&h[r >> RB_LOG], 1); }
    rows[k] = r;
  }
  __syncthreads();

  for (int b = t; b < NBK; b += 256) {
    int c = h[b];
    basea[b] = c ? atomicAdd(&bcur[b], c) : 0;
    h[b] = 0;
  }
  __syncthreads();

  #pragma unroll
  for (int k = 0; k < EPT_A; ++k) {
    int r = rows[k];
    if (r >= 0) {
      long long e = e0 + k * 256 + t;
      int bkt  = r >> RB_LOG;
      int rank = atomicAdd(&h[bkt], 1);
      int pos  = basea[bkt] + rank;
      int pack = ecol[e] | ((r & (RB - 1)) << 18);
      stage[pos] = make_int2(pack, __float_as_int(eval[e]));
    }
  }
}

// ===========================================================================
// Phase B (fused): per-bucket row-count + LDS scan + offs write + permute.
// One block per bucket; window is ~65KB and L2/LLC-hot from phase A.
// ===========================================================================
__global__ __launch_bounds__(256) void bucket_permute_kernel(
    const int*  __restrict__ bbase,
    const int2* __restrict__ stage,
    int2*       __restrict__ ev,
    int*        __restrict__ offs) {
  __shared__ int cnt[RB];   // counts, then becomes per-row cursors
  __shared__ int s[256];
  const int t    = threadIdx.x;
  const int bkt  = blockIdx.x;
  const int row0 = bkt << RB_LOG;
  const int w0   = bbase[bkt];
  const int w1   = bbase[bkt + 1];

  for (int i = t; i < RB; i += 256) cnt[i] = 0;
  __syncthreads();

  // pass 1: per-row count (only the packed .x word is needed)
  for (int i = w0 + t; i < w1; i += 256) {
    int px = ((const int*)stage)[2 * (size_t)i];
    atomicAdd(&cnt[(px >> 18) & (RB - 1)], 1);
  }
  __syncthreads();

  // exclusive scan over 512 counts: 2 elems/thread + 256-wide block scan
  int c0 = cnt[2 * t], c1 = cnt[2 * t + 1];
  int pairsum = c0 + c1;
  s[t] = pairsum;
  __syncthreads();
  for (int off = 1; off < 256; off <<= 1) {
    int v = (t >= off) ? s[t - off] : 0;
    __syncthreads();
    s[t] += v;
    __syncthreads();
  }
  int pexcl = s[t] - pairsum;              // exclusive over pair sums
  int e0 = w0 + pexcl;
  int e1 = e0 + c0;
  cnt[2 * t]     = e0;                     // becomes cursor
  cnt[2 * t + 1] = e1;
  int r0 = row0 + 2 * t;
  if (r0 < N_NODES)     offs[r0]     = e0;
  if (r0 + 1 < N_NODES) offs[r0 + 1] = e1;
  __syncthreads();

  // pass 2: permute into exact row order
  for (int i = w0 + t; i < w1; i += 256) {
    int2 e = stage[i];
    int rl  = (e.x >> 18) & (RB - 1);
    int pos = atomicAdd(&cnt[rl], 1);
    ev[pos] = make_int2(e.x & 0x3FFFF, e.y);
  }
}

// ===========================================================================
// Old single-pass bin (mid-tier fallback)
// ===========================================================================
__global__ __launch_bounds__(256) void bin_kernel(
    const int*   __restrict__ erow,
    const int*   __restrict__ ecol,
    const float* __restrict__ eval,
    int*         __restrict__ cursor,
    int2*        __restrict__ sorted_ev) {
  int base = blockIdx.x * 1024 + threadIdx.x;
  int e0 = base, e1 = base + 256, e2 = base + 512, e3 = base + 768;
  int r0 = (e0 < N_EDGES) ? erow[e0] : 0;
  int r1 = (e1 < N_EDGES) ? erow[e1] : 0;
  int r2 = (e2 < N_EDGES) ? erow[e2] : 0;
  int r3 = (e3 < N_EDGES) ? erow[e3] : 0;
  int p0 = (e0 < N_EDGES) ? atomicAdd(&cursor[r0], 1) : 0;
  int p1 = (e1 < N_EDGES) ? atomicAdd(&cursor[r1], 1) : 0;
  int p2 = (e2 < N_EDGES) ? atomicAdd(&cursor[r2], 1) : 0;
  int p3 = (e3 < N_EDGES) ? atomicAdd(&cursor[r3], 1) : 0;
  if (e0 < N_EDGES) sorted_ev[p0] = make_int2(ecol[e0], __float_as_int(eval[e0]));
  if (e1 < N_EDGES) sorted_ev[p1] = make_int2(ecol[e1], __float_as_int(eval[e1]));
  if (e2 < N_EDGES) sorted_ev[p2] = make_int2(ecol[e2], __float_as_int(eval[e2]));
  if (e3 < N_EDGES) sorted_ev[p3] = make_int2(ecol[e3], __float_as_int(eval[e3]));
}

// ===========================================================================
// ego fp32 -> bf16 conversion
// ===========================================================================
__global__ __launch_bounds__(256) void conv_ego_kernel(
    const float* __restrict__ ego, short* __restrict__ ebf) {
  int i = blockIdx.x * 256 + threadIdx.x;      // float4 slot
  constexpr int TOTAL = N_NODES * D / 4;
  if (i < TOTAL) {
    float4 v = ((const float4*)ego)[i];
    short4v p;
    p[0] = f2bf(v.x); p[1] = f2bf(v.y); p[2] = f2bf(v.z); p[3] = f2bf(v.w);
    ((short4v*)ebf)[i] = p;
  }
}

// ===========================================================================
// Weight prepack: w[k][n] fp32 -> wT[n][k] bf16
// ===========================================================================
__global__ __launch_bounds__(128) void prep_weights_kernel(
    const float* __restrict__ wg, const float* __restrict__ wb,
    short* __restrict__ wtg, short* __restrict__ wtb) {
  int n = blockIdx.x;
  int k = threadIdx.x;
  wtg[n * D + k] = f2bf(wg[k * D + n]);
  wtb[n * D + k] = f2bf(wb[k * D + n]);
}

// ===========================================================================
// SpMM (bf16 ego): one row per 16-lane group, 16B gathers, unroll 4.
// ===========================================================================
__global__ __launch_bounds__(256) void spmm_bf16_kernel(
    const int*   __restrict__ offs,
    const int2*  __restrict__ ev,
    const short* __restrict__ ebf,
    float*       __restrict__ side) {
  const int t = threadIdx.x;
  const int g = t >> 4;
  const int l = t & 15;
  const int row = blockIdx.x * 16 + g;

  const int s0 = offs[row], s1 = offs[row + 1];
  float a0 = 0.f, a1 = 0.f, a2 = 0.f, a3 = 0.f;
  float a4 = 0.f, a5 = 0.f, a6 = 0.f, a7 = 0.f;

  auto accum = [&](int2 e) {
    uint4 u = *(const uint4*)(ebf + (size_t)e.x * D + l * 8);
    float v = __int_as_float(e.y);
    a0 = fmaf(v, __uint_as_float(u.x << 16), a0);
    a1 = fmaf(v, __uint_as_float(u.x & 0xffff0000u), a1);
    a2 = fmaf(v, __uint_as_float(u.y << 16), a2);
    a3 = fmaf(v, __uint_as_float(u.y & 0xffff0000u), a3);
    a4 = fmaf(v, __uint_as_float(u.z << 16), a4);
    a5 = fmaf(v, __uint_as_float(u.z & 0xffff0000u), a5);
    a6 = fmaf(v, __uint_as_float(u.w << 16), a6);
    a7 = fmaf(v, __uint_as_float(u.w & 0xffff0000u), a7);
  };

  int i = s0;
  const int n4 = s0 + ((s1 - s0) & ~3);
  for (; i < n4; i += 4) {
    int2 e0 = ev[i], e1 = ev[i + 1], e2 = ev[i + 2], e3 = ev[i + 3];
    accum(e0); accum(e1); accum(e2); accum(e3);
  }
  for (; i < s1; ++i) accum(ev[i]);

  float* dst = side + (size_t)row * D + l * 8;
  *(float4*)(dst)     = make_float4(a0, a1, a2, a3);
  *(float4*)(dst + 4) = make_float4(a4, a5, a6, a7);
}

// fp32-ego SpMM (sort/mid tiers)
__global__ __launch_bounds__(256) void spmm_kernel(
    const int*  __restrict__ offs,
    const int2* __restrict__ ev,
    const float* __restrict__ ego,
    float*       __restrict__ side) {
  const int t = threadIdx.x;
  const int g = t >> 5;
  const int l = t & 31;
  const int row = blockIdx.x * 8 + g;
  if (row >= N_NODES) return;
  const int s0 = offs[row], s1 = offs[row + 1];
  float ax = 0.f, ay = 0.f, az = 0.f, aw = 0.f;
  int i = s0;
  const int n4 = s0 + ((s1 - s0) & ~3);
  for (; i < n4; i += 4) {
    int2 e0 = ev[i], e1 = ev[i + 1], e2 = ev[i + 2], e3 = ev[i + 3];
    float4 g0 = *(const float4*)(ego + (size_t)e0.x * D + 4 * l);
    float4 g1 = *(const float4*)(ego + (size_t)e1.x * D + 4 * l);
    float4 g2 = *(const float4*)(ego + (size_t)e2.x * D + 4 * l);
    float4 g3 = *(const float4*)(ego + (size_t)e3.x * D + 4 * l);
    float v0 = __int_as_float(e0.y), v1 = __int_as_float(e1.y);
    float v2 = __int_as_float(e2.y), v3 = __int_as_float(e3.y);
    ax = fmaf(v0, g0.x, ax); ay = fmaf(v0, g0.y, ay);
    az = fmaf(v0, g0.z, az); aw = fmaf(v0, g0.w, aw);
    ax = fmaf(v1, g1.x, ax); ay = fmaf(v1, g1.y, ay);
    az = fmaf(v1, g1.z, az); aw = fmaf(v1, g1.w, aw);
    ax = fmaf(v2, g2.x, ax); ay = fmaf(v2, g2.y, ay);
    az = fmaf(v2, g2.z, az); aw = fmaf(v2, g2.w, aw);
    ax = fmaf(v3, g3.x, ax); ay = fmaf(v3, g3.y, ay);
    az = fmaf(v3, g3.z, az); aw = fmaf(v3, g3.w, aw);
  }
  for (; i < s1; ++i) {
    int2 e = ev[i];
    float4 gg = *(const float4*)(ego + (size_t)e.x * D + 4 * l);
    float v = __int_as_float(e.y);
    ax = fmaf(v, gg.x, ax); ay = fmaf(v, gg.y, ay);
    az = fmaf(v, gg.z, az); aw = fmaf(v, gg.w, aw);
  }
  *(float4*)(side + (size_t)row * D + 4 * l) = make_float4(ax, ay, az, aw);
}

// ===========================================================================
// MFMA transform (unchanged)
// ===========================================================================
__global__ __launch_bounds__(256) void transform_mfma_kernel(
    const float* __restrict__ side,
    const float* __restrict__ ego,
    const short* __restrict__ wtg,
    const short* __restrict__ wtb,
    const float* __restrict__ b_gc,
    const float* __restrict__ b_bi,
    float*       __restrict__ out) {
  __shared__ short sA[16][136];
  __shared__ short sP[16][136];
  __shared__ float sO[16][132];
  __shared__ float sInv[16];

  const int t    = threadIdx.x;
  const int w    = t >> 6;
  const int l    = t & 63;
  const int base = blockIdx.x * 16;

  #pragma unroll
  for (int k = 0; k < 2; ++k) {
    int f  = k * 256 + t;
    int r  = f >> 5;
    int c4 = (f & 31) * 4;
    float4 sv = *(const float4*)(side + (size_t)(base + r) * D + c4);
    float4 ev = *(const float4*)(ego  + (size_t)(base + r) * D + c4);
    short4v pa, pp;
    pa[0] = f2bf(sv.x); pa[1] = f2bf(sv.y); pa[2] = f2bf(sv.z); pa[3] = f2bf(sv.w);
    pp[0] = f2bf(sv.x * ev.x); pp[1] = f2bf(sv.y * ev.y);
    pp[2] = f2bf(sv.z * ev.z); pp[3] = f2bf(sv.w * ev.w);
    *(short4v*)&sA[r][c4] = pa;
    *(short4v*)&sP[r][c4] = pp;
  }
  __syncthreads();

  f32x4 accg[2] = {{0.f, 0.f, 0.f, 0.f}, {0.f, 0.f, 0.f, 0.f}};
  f32x4 accb[2] = {{0.f, 0.f, 0.f, 0.f}, {0.f, 0.f, 0.f, 0.f}};

  const int arow = l & 15;
  const int koff = (l >> 4) * 8;
  const int nb   = w * 32;

  #pragma unroll
  for (int ks = 0; ks < 4; ++ks) {
    const int k0 = ks * 32 + koff;
    short8 a_s = *(const short8*)&sA[arow][k0];
    short8 a_p = *(const short8*)&sP[arow][k0];
    #pragma unroll
    for (int ct = 0; ct < 2; ++ct) {
      const int n = nb + ct * 16 + arow;
      short8 bgf = *(const short8*)(wtg + (size_t)n * D + k0);
      short8 bbf = *(const short8*)(wtb + (size_t)n * D + k0);
      accg[ct] = __builtin_amdgcn_mfma_f32_16x16x32_bf16(a_s, bgf, accg[ct], 0, 0, 0);
      accb[ct] = __builtin_amdgcn_mfma_f32_16x16x32_bf16(a_p, bbf, accb[ct], 0, 0, 0);
    }
  }

  #pragma unroll
  for (int ct = 0; ct < 2; ++ct) {
    const int col = nb + ct * 16 + arow;
    const float bg = b_gc[col];
    const float bb = b_bi[col];
    #pragma unroll
    for (int j = 0; j < 4; ++j) {
      const int r = (l >> 4) * 4 + j;
      float x1 = accg[ct][j] + bg; x1 = (x1 > 0.f) ? x1 : LEAKY * x1;
      float x2 = accb[ct][j] + bb; x2 = (x2 > 0.f) ? x2 : LEAKY * x2;
      sO[r][col] = x1 + x2;
    }
  }
  __syncthreads();

  {
    const int r = t >> 4, c16 = t & 15;
    float sum = 0.f;
    #pragma unroll
    for (int i = 0; i < 8; ++i) {
      float v = sO[r][c16 * 8 + i];
      sum = fmaf(v, v, sum);
    }
    #pragma unroll
    for (int off = 8; off > 0; off >>= 1) sum += __shfl_down(sum, off, 16);
    if (c16 == 0) sInv[r] = rsqrtf(fmaxf(sum, L2EPS));
  }
  __syncthreads();

  #pragma unroll
  for (int k = 0; k < 2; ++k) {
    int f  = k * 256 + t;
    int r  = f >> 5;
    int c4 = (f & 31) * 4;
    float inv = sInv[r];
    float4 v = *(const float4*)&sO[r][c4];
    v.x *= inv; v.y *= inv; v.z *= inv; v.w *= inv;
    *(float4*)(out + (size_t)(base + r) * D + c4) = v;
  }
}

// ===========================================================================
// Tiny-workspace fallback
// ===========================================================================
__global__ __launch_bounds__(256) void scatter_kernel(
    const int*   __restrict__ erow,
    const int*   __restrict__ ecol,
    const float* __restrict__ eval,
    const float* __restrict__ ego,
    float*       __restrict__ side) {
  long long t = (long long)blockIdx.x * blockDim.x + threadIdx.x;
  int e = (int)(t >> 5);
  if (e >= N_EDGES) return;
  int c = (int)(t & 31);
  int r  = erow[e];
  int cl = ecol[e];
  float v = eval[e];
  const float4* src = (const float4*)(ego + (long long)cl * D);
  float4 m = src[c];
  float* dst = side + (long long)r * D + c * 4;
  atomicAdd(dst + 0, v * m.x);
  atomicAdd(dst + 1, v * m.y);
  atomicAdd(dst + 2, v * m.z);
  atomicAdd(dst + 3, v * m.w);
}

__global__ __launch_bounds__(128) void transform_f32_kernel(
    const float* __restrict__ side,
    const float* __restrict__ ego,
    const float* __restrict__ w_gc,
    const float* __restrict__ b_gc,
    const float* __restrict__ w_bi,
    const float* __restrict__ b_bi,
    float*       __restrict__ out) {
  constexpr int RPB = 16;
  __shared__ float s_side[RPB][D];
  __shared__ float s_prod[RPB][D];
  __shared__ float s_part[RPB][2];
  const int j    = threadIdx.x;
  const int base = blockIdx.x * RPB;
  #pragma unroll
  for (int r = 0; r < RPB; ++r) {
    int node = base + r;
    float s = 0.f, e = 0.f;
    if (node < N_NODES) {
      s = side[(long long)node * D + j];
      e = ego [(long long)node * D + j];
    }
    s_side[r][j] = s;
    s_prod[r][j] = e * s;
  }
  __syncthreads();
  float acc_gc[RPB], acc_bi[RPB];
  #pragma unroll
  for (int r = 0; r < RPB; ++r) { acc_gc[r] = 0.f; acc_bi[r] = 0.f; }
  for (int k = 0; k < D; ++k) {
    float wg = w_gc[k * D + j];
    float wb = w_bi[k * D + j];
    #pragma unroll
    for (int r = 0; r < RPB; ++r) {
      acc_gc[r] = fmaf(s_side[r][k], wg, acc_gc[r]);
      acc_bi[r] = fmaf(s_prod[r][k], wb, acc_bi[r]);
    }
  }
  const float bg = b_gc[j];
  const float bb = b_bi[j];
  #pragma unroll
  for (int r = 0; r < RPB; ++r) {
    float x1 = acc_gc[r] + bg; x1 = (x1 > 0.f) ? x1 : LEAKY * x1;
    float x2 = acc_bi[r] + bb; x2 = (x2 > 0.f) ? x2 : LEAKY * x2;
    acc_gc[r] = x1 + x2;
  }
  const int lane = j & 63;
  const int wv   = j >> 6;
  #pragma unroll
  for (int r = 0; r < RPB; ++r) {
    float sq = acc_gc[r] * acc_gc[r];
    #pragma unroll
    for (int off = 32; off > 0; off >>= 1) sq += __shfl_down(sq, off, 64);
    if (lane == 0) s_part[r][wv] = sq;
  }
  __syncthreads();
  #pragma unroll
  for (int r = 0; r < RPB; ++r) {
    int node = base + r;
    if (node < N_NODES) {
      float tot = s_part[r][0] + s_part[r][1];
      float inv = rsqrtf(fmaxf(tot, L2EPS));
      out[(long long)node * D + j] = acc_gc[r] * inv;
    }
  }
}

// ===========================================================================
extern "C" void kernel_launch(void* const* d_in, const int* in_sizes, int n_in,
                              void* d_out, int out_size, void* d_ws, size_t ws_size,
                              hipStream_t stream) {
  const int*   erow = (const int*)  d_in[0];
  const int*   ecol = (const int*)  d_in[1];
  const float* eval = (const float*)d_in[2];
  const float* ego  = (const float*)d_in[3];
  const float* w_gc = (const float*)d_in[4];
  const float* b_gc = (const float*)d_in[5];
  const float* w_bi = (const float*)d_in[6];
  const float* b_bi = (const float*)d_in[7];
  float* out = (float*)d_out;

  auto align256 = [](size_t x) { return (x + 255) & ~(size_t)255; };
  size_t off_cnt    = 0;
  size_t off_offs   = align256(off_cnt    + (size_t)N_NODES * 4);
  size_t off_cursor = align256(off_offs   + (size_t)(N_NODES + 1) * 4);
  size_t off_bsums  = align256(off_cursor + (size_t)N_NODES * 4);
  size_t off_bcur   = align256(off_bsums  + 1024 * 4);
  size_t off_wtg    = align256(off_bcur   + (size_t)NBK * 4);
  size_t off_wtb    = align256(off_wtg    + (size_t)D * D * 2);
  size_t off_ev     = align256(off_wtb    + (size_t)D * D * 2);
  size_t off_ebf    = align256(off_ev     + (size_t)N_EDGES * 8);
  size_t ws_mid     = off_ebf;                                   // old bin tier
  size_t ws_sort    = off_ebf + (size_t)N_EDGES * 8;             // bucketed sort, fp32 ego
  size_t ws_full    = off_ebf + (size_t)N_NODES * D * 2;         // + bf16 ego

  if (ws_size >= ws_mid) {
    char* ws = (char*)d_ws;
    int*   cnt    = (int*)  (ws + off_cnt);     // per-row counts (bin tier) / bkt_cnt (bucketed)
    int*   offs   = (int*)  (ws + off_offs);
    int*   cursor = (int*)  (ws + off_cursor);
    int*   bsums  = (int*)  (ws + off_bsums);   // bbase[NBK+1] (bucketed) / scan partials (bin)
    int*   bcur   = (int*)  (ws + off_bcur);
    short* wtg    = (short*)(ws + off_wtg);
    short* wtb    = (short*)(ws + off_wtb);
    int2*  ev     = (int2*) (ws + off_ev);
    short* ebf    = (short*)(ws + off_ebf);
    int2*  stage  = (int2*) (ws + off_ebf);   // aliases ebf; consumed before conv_ego

    float* side = out;   // alias: spmm writes all rows; transform is row-local

    bool bucketed = (ws_size >= ws_sort);
    if (bucketed) {
      // New path: bucket-level histogram (LDS-aggregated), 293-entry scan,
      // then scatter + fused count/scan/permute. No per-row global atomics.
      hipMemsetAsync(cnt, 0, (size_t)NBK * 4, stream);
      bucket_hist_kernel<<<(N_EDGES + EPB_A - 1) / EPB_A, 256, 0, stream>>>(erow, cnt);
      bucket_scan_kernel<<<1, 512, 0, stream>>>(cnt, bsums, bcur, offs);
      bucket_scatter_kernel<<<(N_EDGES + EPB_A - 1) / EPB_A, 256, 0, stream>>>(
          erow, ecol, eval, bcur, stage);
      bucket_permute_kernel<<<NBK, 256, 0, stream>>>(bsums, stage, ev, offs);
    } else {
      // Old path for the mid tier (needs per-row cursor).
      hipMemsetAsync(cnt, 0, (size_t)N_NODES * 4, stream);
      hist_kernel<<<(N_EDGES + 2047) / 2048, 256, 0, stream>>>(erow, cnt);
      scan_block_sums<<<NB_SCAN, 256, 0, stream>>>(cnt, bsums);
      scan_partials<<<1, 1024, 0, stream>>>(bsums);
      scan_final<<<NB_SCAN, 256, 0, stream>>>(cnt, bsums, offs, cursor);
      bin_kernel<<<(N_EDGES + 1023) / 1024, 256, 0, stream>>>(
          erow, ecol, eval, cursor, ev);
    }
    prep_weights_kernel<<<D, D, 0, stream>>>(w_gc, w_bi, wtg, wtb);

    if (ws_size >= ws_full) {
      conv_ego_kernel<<<(N_NODES * D / 4 + 255) / 256, 256, 0, stream>>>(ego, ebf);
      spmm_bf16_kernel<<<N_NODES / 16, 256, 0, stream>>>(offs, ev, ebf, side);
    } else {
      spmm_kernel<<<(N_NODES + 7) / 8, 256, 0, stream>>>(offs, ev, ego, side);
    }
    transform_mfma_kernel<<<N_NODES / 16, 256, 0, stream>>>(
        side, ego, wtg, wtb, b_gc, b_bi, out);
  } else {
    float* side = out;
    hipMemsetAsync(side, 0, (size_t)N_NODES * D * 4, stream);
    long long total = (long long)N_EDGES * 32;
    int grid = (int)((total + 255) / 256);
    scatter_kernel<<<grid, 256, 0, stream>>>(erow, ecol, eval, ego, side);
    transform_f32_kernel<<<N_NODES / 16, 128, 0, stream>>>(
        side, ego, w_gc, b_gc, w_bi, b_bi, out);
  }
}

// Round 3
// 409.806 us; speedup vs baseline: 1.2475x; 1.0688x over previous
//
#include <hip/hip_runtime.h>
#include <hip/hip_bf16.h>

constexpr int N_NODES = 150000;
constexpr int N_EDGES = 2400000;
constexpr int D       = 128;
constexpr float LEAKY = 0.2f;
constexpr float L2EPS = 1e-12f;

constexpr int NB_SCAN = (N_NODES + 255) / 256;   // 586 (<1024)

// Bucket sort params
constexpr int RB_LOG = 9;                               // 512 rows / bucket
constexpr int RB     = 1 << RB_LOG;
constexpr int NBK    = (N_NODES + RB - 1) >> RB_LOG;    // 293
constexpr int EPT_A  = 32;                              // edges / thread, phase A
constexpr int EPB_A  = 256 * EPT_A;                     // 8192 edges / block

typedef short  short8  __attribute__((ext_vector_type(8)));
typedef short  short4v __attribute__((ext_vector_type(4)));
typedef float  f32x4   __attribute__((ext_vector_type(4)));

static __device__ __forceinline__ short f2bf(float x) {
  __hip_bfloat16 h = __float2bfloat16(x);
  return *reinterpret_cast<short*>(&h);
}

// ===========================================================================
// Bucket-level histogram (LDS-aggregated -> 293 global atomics / block)
// ===========================================================================
__global__ __launch_bounds__(256) void bucket_hist_kernel(
    const int* __restrict__ erow, int* __restrict__ bkt_cnt) {
  __shared__ int h[NBK];
  const int t = threadIdx.x;
  for (int i = t; i < NBK; i += 256) h[i] = 0;
  __syncthreads();
  const long long e0 = (long long)blockIdx.x * EPB_A;
  #pragma unroll
  for (int k = 0; k < EPT_A; ++k) {
    long long e = e0 + k * 256 + t;
    if (e < N_EDGES) atomicAdd(&h[erow[e] >> RB_LOG], 1);
  }
  __syncthreads();
  for (int i = t; i < NBK; i += 256) {
    int c = h[i];
    if (c) atomicAdd(&bkt_cnt[i], c);
  }
}

// Single-block exclusive scan over the 293 bucket counts.
__global__ __launch_bounds__(512) void bucket_scan_kernel(
    const int* __restrict__ bkt_cnt,
    int* __restrict__ bbase,        // NBK+1 entries
    int* __restrict__ bcur,
    int* __restrict__ offs) {
  __shared__ int s[512];
  const int t = threadIdx.x;
  int v = (t < NBK) ? bkt_cnt[t] : 0;
  s[t] = v;
  __syncthreads();
  for (int off = 1; off < 512; off <<= 1) {
    int tmp = (t >= off) ? s[t - off] : 0;
    __syncthreads();
    s[t] += tmp;
    __syncthreads();
  }
  if (t < NBK) {
    int excl = s[t] - v;
    bbase[t] = excl;
    bcur[t]  = excl;
  }
  if (t == 0) { bbase[NBK] = N_EDGES; offs[N_NODES] = N_EDGES; }
}

// ===========================================================================
// Old per-row histogram + scans (kept for the mid-tier bin fallback only)
// ===========================================================================
__global__ __launch_bounds__(256) void hist_kernel(
    const int* __restrict__ erow, int* __restrict__ cnt) {
  int base = blockIdx.x * 2048 + threadIdx.x;
  #pragma unroll
  for (int k = 0; k < 8; ++k) {
    int e = base + k * 256;
    if (e < N_EDGES) atomicAdd(&cnt[erow[e]], 1);
  }
}

__global__ __launch_bounds__(256) void scan_block_sums(
    const int* __restrict__ cnt, int* __restrict__ bsums) {
  __shared__ int s[256];
  int i = blockIdx.x * 256 + threadIdx.x;
  s[threadIdx.x] = (i < N_NODES) ? cnt[i] : 0;
  __syncthreads();
  for (int off = 128; off > 0; off >>= 1) {
    if (threadIdx.x < off) s[threadIdx.x] += s[threadIdx.x + off];
    __syncthreads();
  }
  if (threadIdx.x == 0) bsums[blockIdx.x] = s[0];
}

__global__ __launch_bounds__(1024) void scan_partials(int* __restrict__ bsums) {
  __shared__ int s[1024];
  int v = (threadIdx.x < NB_SCAN) ? bsums[threadIdx.x] : 0;
  s[threadIdx.x] = v;
  __syncthreads();
  for (int off = 1; off < 1024; off <<= 1) {
    int t = (threadIdx.x >= off) ? s[threadIdx.x - off] : 0;
    __syncthreads();
    s[threadIdx.x] += t;
    __syncthreads();
  }
  if (threadIdx.x < NB_SCAN) bsums[threadIdx.x] = s[threadIdx.x] - v;  // exclusive
}

__global__ __launch_bounds__(256) void scan_final(
    const int* __restrict__ cnt, const int* __restrict__ bsums,
    int* __restrict__ offs, int* __restrict__ cursor) {
  __shared__ int s[256];
  int i = blockIdx.x * 256 + threadIdx.x;
  int v = (i < N_NODES) ? cnt[i] : 0;
  s[threadIdx.x] = v;
  __syncthreads();
  for (int off = 1; off < 256; off <<= 1) {
    int t = (threadIdx.x >= off) ? s[threadIdx.x - off] : 0;
    __syncthreads();
    s[threadIdx.x] += t;
    __syncthreads();
  }
  if (i < N_NODES) {
    int excl = s[threadIdx.x] - v + bsums[blockIdx.x];
    offs[i]   = excl;
    cursor[i] = excl;
  }
  if (i == 0) offs[N_NODES] = N_EDGES;
}

// ===========================================================================
// Phase A: bucket scatter with coalesced run-writes into stage.
// ===========================================================================
__global__ __launch_bounds__(256) void bucket_scatter_kernel(
    const int*   __restrict__ erow,
    const int*   __restrict__ ecol,
    const float* __restrict__ eval,
    int*         __restrict__ bcur,
    int2*        __restrict__ stage) {
  __shared__ int h[NBK];
  __shared__ int basea[NBK];
  const int t = threadIdx.x;
  const long long e0 = (long long)blockIdx.x * EPB_A;

  for (int i = t; i < NBK; i += 256) h[i] = 0;
  __syncthreads();

  int rows[EPT_A];
  #pragma unroll
  for (int k = 0; k < EPT_A; ++k) {
    long long e = e0 + k * 256 + t;
    int r = -1;
    if (e < N_EDGES) { r = erow[e]; atomicAdd(&h[r >> RB_LOG], 1); }
    rows[k] = r;
  }
  __syncthreads();

  for (int b = t; b < NBK; b += 256) {
    int c = h[b];
    basea[b] = c ? atomicAdd(&bcur[b], c) : 0;
    h[b] = 0;
  }
  __syncthreads();

  #pragma unroll
  for (int k = 0; k < EPT_A; ++k) {
    int r = rows[k];
    if (r >= 0) {
      long long e = e0 + k * 256 + t;
      int bkt  = r >> RB_LOG;
      int rank = atomicAdd(&h[bkt], 1);
      int pos  = basea[bkt] + rank;
      int pack = ecol[e] | ((r & (RB - 1)) << 18);
      stage[pos] = make_int2(pack, __float_as_int(eval[e]));
    }
  }
}

// ===========================================================================
// Phase B (fused): per-bucket row-count + LDS scan + offs write + permute.
// ===========================================================================
__global__ __launch_bounds__(256) void bucket_permute_kernel(
    const int*  __restrict__ bbase,
    const int2* __restrict__ stage,
    int2*       __restrict__ ev,
    int*        __restrict__ offs) {
  __shared__ int cnt[RB];   // counts, then becomes per-row cursors
  __shared__ int s[256];
  const int t    = threadIdx.x;
  const int bkt  = blockIdx.x;
  const int row0 = bkt << RB_LOG;
  const int w0   = bbase[bkt];
  const int w1   = bbase[bkt + 1];

  for (int i = t; i < RB; i += 256) cnt[i] = 0;
  __syncthreads();

  // pass 1: per-row count (only the packed .x word is needed)
  for (int i = w0 + t; i < w1; i += 256) {
    int px = ((const int*)stage)[2 * (size_t)i];
    atomicAdd(&cnt[(px >> 18) & (RB - 1)], 1);
  }
  __syncthreads();

  // exclusive scan over 512 counts: 2 elems/thread + 256-wide block scan
  int c0 = cnt[2 * t], c1 = cnt[2 * t + 1];
  int pairsum = c0 + c1;
  s[t] = pairsum;
  __syncthreads();
  for (int off = 1; off < 256; off <<= 1) {
    int v = (t >= off) ? s[t - off] : 0;
    __syncthreads();
    s[t] += v;
    __syncthreads();
  }
  int pexcl = s[t] - pairsum;              // exclusive over pair sums
  int e0 = w0 + pexcl;
  int e1 = e0 + c0;
  cnt[2 * t]     = e0;                     // becomes cursor
  cnt[2 * t + 1] = e1;
  int r0 = row0 + 2 * t;
  if (r0 < N_NODES)     offs[r0]     = e0;
  if (r0 + 1 < N_NODES) offs[r0 + 1] = e1;
  __syncthreads();

  // pass 2: permute into exact row order
  for (int i = w0 + t; i < w1; i += 256) {
    int2 e = stage[i];
    int rl  = (e.x >> 18) & (RB - 1);
    int pos = atomicAdd(&cnt[rl], 1);
    ev[pos] = make_int2(e.x & 0x3FFFF, e.y);
  }
}

// ===========================================================================
// Old single-pass bin (mid-tier fallback)
// ===========================================================================
__global__ __launch_bounds__(256) void bin_kernel(
    const int*   __restrict__ erow,
    const int*   __restrict__ ecol,
    const float* __restrict__ eval,
    int*         __restrict__ cursor,
    int2*        __restrict__ sorted_ev) {
  int base = blockIdx.x * 1024 + threadIdx.x;
  int e0 = base, e1 = base + 256, e2 = base + 512, e3 = base + 768;
  int r0 = (e0 < N_EDGES) ? erow[e0] : 0;
  int r1 = (e1 < N_EDGES) ? erow[e1] : 0;
  int r2 = (e2 < N_EDGES) ? erow[e2] : 0;
  int r3 = (e3 < N_EDGES) ? erow[e3] : 0;
  int p0 = (e0 < N_EDGES) ? atomicAdd(&cursor[r0], 1) : 0;
  int p1 = (e1 < N_EDGES) ? atomicAdd(&cursor[r1], 1) : 0;
  int p2 = (e2 < N_EDGES) ? atomicAdd(&cursor[r2], 1) : 0;
  int p3 = (e3 < N_EDGES) ? atomicAdd(&cursor[r3], 1) : 0;
  if (e0 < N_EDGES) sorted_ev[p0] = make_int2(ecol[e0], __float_as_int(eval[e0]));
  if (e1 < N_EDGES) sorted_ev[p1] = make_int2(ecol[e1], __float_as_int(eval[e1]));
  if (e2 < N_EDGES) sorted_ev[p2] = make_int2(ecol[e2], __float_as_int(eval[e2]));
  if (e3 < N_EDGES) sorted_ev[p3] = make_int2(ecol[e3], __float_as_int(eval[e3]));
}

// ===========================================================================
// ego fp32 -> bf16 conversion
// ===========================================================================
__global__ __launch_bounds__(256) void conv_ego_kernel(
    const float* __restrict__ ego, short* __restrict__ ebf) {
  int i = blockIdx.x * 256 + threadIdx.x;      // float4 slot
  constexpr int TOTAL = N_NODES * D / 4;
  if (i < TOTAL) {
    float4 v = ((const float4*)ego)[i];
    short4v p;
    p[0] = f2bf(v.x); p[1] = f2bf(v.y); p[2] = f2bf(v.z); p[3] = f2bf(v.w);
    ((short4v*)ebf)[i] = p;
  }
}

// ===========================================================================
// Weight prepack: w[k][n] fp32 -> wT[n][k] bf16
// ===========================================================================
__global__ __launch_bounds__(128) void prep_weights_kernel(
    const float* __restrict__ wg, const float* __restrict__ wb,
    short* __restrict__ wtg, short* __restrict__ wtb) {
  int n = blockIdx.x;
  int k = threadIdx.x;
  wtg[n * D + k] = f2bf(wg[k * D + n]);
  wtb[n * D + k] = f2bf(wb[k * D + n]);
}

// ===========================================================================
// FUSED SpMM + transform + L2-normalize.
// Block = 16 rows, 256 threads. Gather phase: one row per 16-lane group,
// side row held in registers (a0..a7 per lane). Then staged directly to LDS
// as bf16(side) and bf16(side*ego) -> MFMA dual-GEMM -> leaky -> l2norm.
// Eliminates the side write (75 MB) + side read (77 MB) round-trip.
// ===========================================================================
__global__ __launch_bounds__(256) void spmm_transform_kernel(
    const int*   __restrict__ offs,
    const int2*  __restrict__ ev,
    const short* __restrict__ ebf,
    const float* __restrict__ ego,
    const short* __restrict__ wtg,
    const short* __restrict__ wtb,
    const float* __restrict__ b_gc,
    const float* __restrict__ b_bi,
    float*       __restrict__ out) {
  __shared__ short sA[16][136];
  __shared__ short sP[16][136];
  __shared__ float sO[16][132];
  __shared__ float sInv[16];

  const int t    = threadIdx.x;
  const int g    = t >> 4;
  const int lg   = t & 15;
  const int base = blockIdx.x * 16;
  const int row  = base + g;

  // ---- phase 1: SpMM gather (row in registers) ----
  const int s0 = offs[row], s1 = offs[row + 1];
  float a0 = 0.f, a1 = 0.f, a2 = 0.f, a3 = 0.f;
  float a4 = 0.f, a5 = 0.f, a6 = 0.f, a7 = 0.f;

  auto accum = [&](int2 e) {
    uint4 u = *(const uint4*)(ebf + (size_t)e.x * D + lg * 8);
    float v = __int_as_float(e.y);
    a0 = fmaf(v, __uint_as_float(u.x << 16), a0);
    a1 = fmaf(v, __uint_as_float(u.x & 0xffff0000u), a1);
    a2 = fmaf(v, __uint_as_float(u.y << 16), a2);
    a3 = fmaf(v, __uint_as_float(u.y & 0xffff0000u), a3);
    a4 = fmaf(v, __uint_as_float(u.z << 16), a4);
    a5 = fmaf(v, __uint_as_float(u.z & 0xffff0000u), a5);
    a6 = fmaf(v, __uint_as_float(u.w << 16), a6);
    a7 = fmaf(v, __uint_as_float(u.w & 0xffff0000u), a7);
  };

  int i = s0;
  const int n4 = s0 + ((s1 - s0) & ~3);
  for (; i < n4; i += 4) {
    int2 e0 = ev[i], e1 = ev[i + 1], e2 = ev[i + 2], e3 = ev[i + 3];
    accum(e0); accum(e1); accum(e2); accum(e3);
  }
  for (; i < s1; ++i) accum(ev[i]);

  // ---- phase 2: stage bf16(side), bf16(side*ego) into LDS ----
  {
    const float* er = ego + (size_t)row * D + lg * 8;
    float4 ev0 = *(const float4*)(er);
    float4 ev1 = *(const float4*)(er + 4);
    short4v pa0, pa1, pp0, pp1;
    pa0[0] = f2bf(a0); pa0[1] = f2bf(a1); pa0[2] = f2bf(a2); pa0[3] = f2bf(a3);
    pa1[0] = f2bf(a4); pa1[1] = f2bf(a5); pa1[2] = f2bf(a6); pa1[3] = f2bf(a7);
    pp0[0] = f2bf(a0 * ev0.x); pp0[1] = f2bf(a1 * ev0.y);
    pp0[2] = f2bf(a2 * ev0.z); pp0[3] = f2bf(a3 * ev0.w);
    pp1[0] = f2bf(a4 * ev1.x); pp1[1] = f2bf(a5 * ev1.y);
    pp1[2] = f2bf(a6 * ev1.z); pp1[3] = f2bf(a7 * ev1.w);
    *(short4v*)&sA[g][lg * 8]     = pa0;
    *(short4v*)&sA[g][lg * 8 + 4] = pa1;
    *(short4v*)&sP[g][lg * 8]     = pp0;
    *(short4v*)&sP[g][lg * 8 + 4] = pp1;
  }
  __syncthreads();

  // ---- phase 3: dual MFMA GEMM + bias + leaky ----
  {
    const int w    = t >> 6;
    const int l64  = t & 63;
    const int arow = l64 & 15;
    const int koff = (l64 >> 4) * 8;
    const int nb   = w * 32;

    f32x4 accg[2] = {{0.f, 0.f, 0.f, 0.f}, {0.f, 0.f, 0.f, 0.f}};
    f32x4 accb[2] = {{0.f, 0.f, 0.f, 0.f}, {0.f, 0.f, 0.f, 0.f}};

    #pragma unroll
    for (int ks = 0; ks < 4; ++ks) {
      const int k0 = ks * 32 + koff;
      short8 a_s = *(const short8*)&sA[arow][k0];
      short8 a_p = *(const short8*)&sP[arow][k0];
      #pragma unroll
      for (int ct = 0; ct < 2; ++ct) {
        const int n = nb + ct * 16 + arow;
        short8 bgf = *(const short8*)(wtg + (size_t)n * D + k0);
        short8 bbf = *(const short8*)(wtb + (size_t)n * D + k0);
        accg[ct] = __builtin_amdgcn_mfma_f32_16x16x32_bf16(a_s, bgf, accg[ct], 0, 0, 0);
        accb[ct] = __builtin_amdgcn_mfma_f32_16x16x32_bf16(a_p, bbf, accb[ct], 0, 0, 0);
      }
    }

    #pragma unroll
    for (int ct = 0; ct < 2; ++ct) {
      const int col = nb + ct * 16 + arow;
      const float bg = b_gc[col];
      const float bb = b_bi[col];
      #pragma unroll
      for (int j = 0; j < 4; ++j) {
        const int r = (l64 >> 4) * 4 + j;
        float x1 = accg[ct][j] + bg; x1 = (x1 > 0.f) ? x1 : LEAKY * x1;
        float x2 = accb[ct][j] + bb; x2 = (x2 > 0.f) ? x2 : LEAKY * x2;
        sO[r][col] = x1 + x2;
      }
    }
  }
  __syncthreads();

  // ---- phase 4: row L2-norm ----
  {
    const int r = t >> 4, c16 = t & 15;
    float sum = 0.f;
    #pragma unroll
    for (int i2 = 0; i2 < 8; ++i2) {
      float v = sO[r][c16 * 8 + i2];
      sum = fmaf(v, v, sum);
    }
    #pragma unroll
    for (int off = 8; off > 0; off >>= 1) sum += __shfl_down(sum, off, 16);
    if (c16 == 0) sInv[r] = rsqrtf(fmaxf(sum, L2EPS));
  }
  __syncthreads();

  #pragma unroll
  for (int k = 0; k < 2; ++k) {
    int f  = k * 256 + t;
    int r  = f >> 5;
    int c4 = (f & 31) * 4;
    float inv = sInv[r];
    float4 v = *(const float4*)&sO[r][c4];
    v.x *= inv; v.y *= inv; v.z *= inv; v.w *= inv;
    *(float4*)(out + (size_t)(base + r) * D + c4) = v;
  }
}

// fp32-ego SpMM (sort/mid tiers)
__global__ __launch_bounds__(256) void spmm_kernel(
    const int*  __restrict__ offs,
    const int2* __restrict__ ev,
    const float* __restrict__ ego,
    float*       __restrict__ side) {
  const int t = threadIdx.x;
  const int g = t >> 5;
  const int l = t & 31;
  const int row = blockIdx.x * 8 + g;
  if (row >= N_NODES) return;
  const int s0 = offs[row], s1 = offs[row + 1];
  float ax = 0.f, ay = 0.f, az = 0.f, aw = 0.f;
  int i = s0;
  const int n4 = s0 + ((s1 - s0) & ~3);
  for (; i < n4; i += 4) {
    int2 e0 = ev[i], e1 = ev[i + 1], e2 = ev[i + 2], e3 = ev[i + 3];
    float4 g0 = *(const float4*)(ego + (size_t)e0.x * D + 4 * l);
    float4 g1 = *(const float4*)(ego + (size_t)e1.x * D + 4 * l);
    float4 g2 = *(const float4*)(ego + (size_t)e2.x * D + 4 * l);
    float4 g3 = *(const float4*)(ego + (size_t)e3.x * D + 4 * l);
    float v0 = __int_as_float(e0.y), v1 = __int_as_float(e1.y);
    float v2 = __int_as_float(e2.y), v3 = __int_as_float(e3.y);
    ax = fmaf(v0, g0.x, ax); ay = fmaf(v0, g0.y, ay);
    az = fmaf(v0, g0.z, az); aw = fmaf(v0, g0.w, aw);
    ax = fmaf(v1, g1.x, ax); ay = fmaf(v1, g1.y, ay);
    az = fmaf(v1, g1.z, az); aw = fmaf(v1, g1.w, aw);
    ax = fmaf(v2, g2.x, ax); ay = fmaf(v2, g2.y, ay);
    az = fmaf(v2, g2.z, az); aw = fmaf(v2, g2.w, aw);
    ax = fmaf(v3, g3.x, ax); ay = fmaf(v3, g3.y, ay);
    az = fmaf(v3, g3.z, az); aw = fmaf(v3, g3.w, aw);
  }
  for (; i < s1; ++i) {
    int2 e = ev[i];
    float4 gg = *(const float4*)(ego + (size_t)e.x * D + 4 * l);
    float v = __int_as_float(e.y);
    ax = fmaf(v, gg.x, ax); ay = fmaf(v, gg.y, ay);
    az = fmaf(v, gg.z, az); aw = fmaf(v, gg.w, aw);
  }
  *(float4*)(side + (size_t)row * D + 4 * l) = make_float4(ax, ay, az, aw);
}

// ===========================================================================
// Standalone MFMA transform (non-full tiers)
// ===========================================================================
__global__ __launch_bounds__(256) void transform_mfma_kernel(
    const float* __restrict__ side,
    const float* __restrict__ ego,
    const short* __restrict__ wtg,
    const short* __restrict__ wtb,
    const float* __restrict__ b_gc,
    const float* __restrict__ b_bi,
    float*       __restrict__ out) {
  __shared__ short sA[16][136];
  __shared__ short sP[16][136];
  __shared__ float sO[16][132];
  __shared__ float sInv[16];

  const int t    = threadIdx.x;
  const int w    = t >> 6;
  const int l    = t & 63;
  const int base = blockIdx.x * 16;

  #pragma unroll
  for (int k = 0; k < 2; ++k) {
    int f  = k * 256 + t;
    int r  = f >> 5;
    int c4 = (f & 31) * 4;
    float4 sv = *(const float4*)(side + (size_t)(base + r) * D + c4);
    float4 ev = *(const float4*)(ego  + (size_t)(base + r) * D + c4);
    short4v pa, pp;
    pa[0] = f2bf(sv.x); pa[1] = f2bf(sv.y); pa[2] = f2bf(sv.z); pa[3] = f2bf(sv.w);
    pp[0] = f2bf(sv.x * ev.x); pp[1] = f2bf(sv.y * ev.y);
    pp[2] = f2bf(sv.z * ev.z); pp[3] = f2bf(sv.w * ev.w);
    *(short4v*)&sA[r][c4] = pa;
    *(short4v*)&sP[r][c4] = pp;
  }
  __syncthreads();

  f32x4 accg[2] = {{0.f, 0.f, 0.f, 0.f}, {0.f, 0.f, 0.f, 0.f}};
  f32x4 accb[2] = {{0.f, 0.f, 0.f, 0.f}, {0.f, 0.f, 0.f, 0.f}};

  const int arow = l & 15;
  const int koff = (l >> 4) * 8;
  const int nb   = w * 32;

  #pragma unroll
  for (int ks = 0; ks < 4; ++ks) {
    const int k0 = ks * 32 + koff;
    short8 a_s = *(const short8*)&sA[arow][k0];
    short8 a_p = *(const short8*)&sP[arow][k0];
    #pragma unroll
    for (int ct = 0; ct < 2; ++ct) {
      const int n = nb + ct * 16 + arow;
      short8 bgf = *(const short8*)(wtg + (size_t)n * D + k0);
      short8 bbf = *(const short8*)(wtb + (size_t)n * D + k0);
      accg[ct] = __builtin_amdgcn_mfma_f32_16x16x32_bf16(a_s, bgf, accg[ct], 0, 0, 0);
      accb[ct] = __builtin_amdgcn_mfma_f32_16x16x32_bf16(a_p, bbf, accb[ct], 0, 0, 0);
    }
  }

  #pragma unroll
  for (int ct = 0; ct < 2; ++ct) {
    const int col = nb + ct * 16 + arow;
    const float bg = b_gc[col];
    const float bb = b_bi[col];
    #pragma unroll
    for (int j = 0; j < 4; ++j) {
      const int r = (l >> 4) * 4 + j;
      float x1 = accg[ct][j] + bg; x1 = (x1 > 0.f) ? x1 : LEAKY * x1;
      float x2 = accb[ct][j] + bb; x2 = (x2 > 0.f) ? x2 : LEAKY * x2;
      sO[r][col] = x1 + x2;
    }
  }
  __syncthreads();

  {
    const int r = t >> 4, c16 = t & 15;
    float sum = 0.f;
    #pragma unroll
    for (int i = 0; i < 8; ++i) {
      float v = sO[r][c16 * 8 + i];
      sum = fmaf(v, v, sum);
    }
    #pragma unroll
    for (int off = 8; off > 0; off >>= 1) sum += __shfl_down(sum, off, 16);
    if (c16 == 0) sInv[r] = rsqrtf(fmaxf(sum, L2EPS));
  }
  __syncthreads();

  #pragma unroll
  for (int k = 0; k < 2; ++k) {
    int f  = k * 256 + t;
    int r  = f >> 5;
    int c4 = (f & 31) * 4;
    float inv = sInv[r];
    float4 v = *(const float4*)&sO[r][c4];
    v.x *= inv; v.y *= inv; v.z *= inv; v.w *= inv;
    *(float4*)(out + (size_t)(base + r) * D + c4) = v;
  }
}

// ===========================================================================
// Tiny-workspace fallback
// ===========================================================================
__global__ __launch_bounds__(256) void scatter_kernel(
    const int*   __restrict__ erow,
    const int*   __restrict__ ecol,
    const float* __restrict__ eval,
    const float* __restrict__ ego,
    float*       __restrict__ side) {
  long long t = (long long)blockIdx.x * blockDim.x + threadIdx.x;
  int e = (int)(t >> 5);
  if (e >= N_EDGES) return;
  int c = (int)(t & 31);
  int r  = erow[e];
  int cl = ecol[e];
  float v = eval[e];
  const float4* src = (const float4*)(ego + (long long)cl * D);
  float4 m = src[c];
  float* dst = side + (long long)r * D + c * 4;
  atomicAdd(dst + 0, v * m.x);
  atomicAdd(dst + 1, v * m.y);
  atomicAdd(dst + 2, v * m.z);
  atomicAdd(dst + 3, v * m.w);
}

__global__ __launch_bounds__(128) void transform_f32_kernel(
    const float* __restrict__ side,
    const float* __restrict__ ego,
    const float* __restrict__ w_gc,
    const float* __restrict__ b_gc,
    const float* __restrict__ w_bi,
    const float* __restrict__ b_bi,
    float*       __restrict__ out) {
  constexpr int RPB = 16;
  __shared__ float s_side[RPB][D];
  __shared__ float s_prod[RPB][D];
  __shared__ float s_part[RPB][2];
  const int j    = threadIdx.x;
  const int base = blockIdx.x * RPB;
  #pragma unroll
  for (int r = 0; r < RPB; ++r) {
    int node = base + r;
    float s = 0.f, e = 0.f;
    if (node < N_NODES) {
      s = side[(long long)node * D + j];
      e = ego [(long long)node * D + j];
    }
    s_side[r][j] = s;
    s_prod[r][j] = e * s;
  }
  __syncthreads();
  float acc_gc[RPB], acc_bi[RPB];
  #pragma unroll
  for (int r = 0; r < RPB; ++r) { acc_gc[r] = 0.f; acc_bi[r] = 0.f; }
  for (int k = 0; k < D; ++k) {
    float wg = w_gc[k * D + j];
    float wb = w_bi[k * D + j];
    #pragma unroll
    for (int r = 0; r < RPB; ++r) {
      acc_gc[r] = fmaf(s_side[r][k], wg, acc_gc[r]);
      acc_bi[r] = fmaf(s_prod[r][k], wb, acc_bi[r]);
    }
  }
  const float bg = b_gc[j];
  const float bb = b_bi[j];
  #pragma unroll
  for (int r = 0; r < RPB; ++r) {
    float x1 = acc_gc[r] + bg; x1 = (x1 > 0.f) ? x1 : LEAKY * x1;
    float x2 = acc_bi[r] + bb; x2 = (x2 > 0.f) ? x2 : LEAKY * x2;
    acc_gc[r] = x1 + x2;
  }
  const int lane = j & 63;
  const int wv   = j >> 6;
  #pragma unroll
  for (int r = 0; r < RPB; ++r) {
    float sq = acc_gc[r] * acc_gc[r];
    #pragma unroll
    for (int off = 32; off > 0; off >>= 1) sq += __shfl_down(sq, off, 64);
    if (lane == 0) s_part[r][wv] = sq;
  }
  __syncthreads();
  #pragma unroll
  for (int r = 0; r < RPB; ++r) {
    int node = base + r;
    if (node < N_NODES) {
      float tot = s_part[r][0] + s_part[r][1];
      float inv = rsqrtf(fmaxf(tot, L2EPS));
      out[(long long)node * D + j] = acc_gc[r] * inv;
    }
  }
}

// ===========================================================================
extern "C" void kernel_launch(void* const* d_in, const int* in_sizes, int n_in,
                              void* d_out, int out_size, void* d_ws, size_t ws_size,
                              hipStream_t stream) {
  const int*   erow = (const int*)  d_in[0];
  const int*   ecol = (const int*)  d_in[1];
  const float* eval = (const float*)d_in[2];
  const float* ego  = (const float*)d_in[3];
  const float* w_gc = (const float*)d_in[4];
  const float* b_gc = (const float*)d_in[5];
  const float* w_bi = (const float*)d_in[6];
  const float* b_bi = (const float*)d_in[7];
  float* out = (float*)d_out;

  auto align256 = [](size_t x) { return (x + 255) & ~(size_t)255; };
  size_t off_cnt    = 0;
  size_t off_offs   = align256(off_cnt    + (size_t)N_NODES * 4);
  size_t off_cursor = align256(off_offs   + (size_t)(N_NODES + 1) * 4);
  size_t off_bsums  = align256(off_cursor + (size_t)N_NODES * 4);
  size_t off_bcur   = align256(off_bsums  + 1024 * 4);
  size_t off_wtg    = align256(off_bcur   + (size_t)NBK * 4);
  size_t off_wtb    = align256(off_wtg    + (size_t)D * D * 2);
  size_t off_ev     = align256(off_wtb    + (size_t)D * D * 2);
  size_t off_ebf    = align256(off_ev     + (size_t)N_EDGES * 8);
  size_t ws_mid     = off_ebf;                                   // old bin tier
  size_t ws_sort    = off_ebf + (size_t)N_EDGES * 8;             // bucketed sort, fp32 ego
  size_t ws_full    = off_ebf + (size_t)N_NODES * D * 2;         // + bf16 ego

  if (ws_size >= ws_mid) {
    char* ws = (char*)d_ws;
    int*   cnt    = (int*)  (ws + off_cnt);     // per-row counts (bin tier) / bkt_cnt (bucketed)
    int*   offs   = (int*)  (ws + off_offs);
    int*   cursor = (int*)  (ws + off_cursor);
    int*   bsums  = (int*)  (ws + off_bsums);   // bbase[NBK+1] (bucketed) / scan partials (bin)
    int*   bcur   = (int*)  (ws + off_bcur);
    short* wtg    = (short*)(ws + off_wtg);
    short* wtb    = (short*)(ws + off_wtb);
    int2*  ev     = (int2*) (ws + off_ev);
    short* ebf    = (short*)(ws + off_ebf);
    int2*  stage  = (int2*) (ws + off_ebf);   // aliases ebf; consumed before conv_ego

    bool bucketed = (ws_size >= ws_sort);
    if (bucketed) {
      hipMemsetAsync(cnt, 0, (size_t)NBK * 4, stream);
      bucket_hist_kernel<<<(N_EDGES + EPB_A - 1) / EPB_A, 256, 0, stream>>>(erow, cnt);
      bucket_scan_kernel<<<1, 512, 0, stream>>>(cnt, bsums, bcur, offs);
      bucket_scatter_kernel<<<(N_EDGES + EPB_A - 1) / EPB_A, 256, 0, stream>>>(
          erow, ecol, eval, bcur, stage);
      bucket_permute_kernel<<<NBK, 256, 0, stream>>>(bsums, stage, ev, offs);
    } else {
      hipMemsetAsync(cnt, 0, (size_t)N_NODES * 4, stream);
      hist_kernel<<<(N_EDGES + 2047) / 2048, 256, 0, stream>>>(erow, cnt);
      scan_block_sums<<<NB_SCAN, 256, 0, stream>>>(cnt, bsums);
      scan_partials<<<1, 1024, 0, stream>>>(bsums);
      scan_final<<<NB_SCAN, 256, 0, stream>>>(cnt, bsums, offs, cursor);
      bin_kernel<<<(N_EDGES + 1023) / 1024, 256, 0, stream>>>(
          erow, ecol, eval, cursor, ev);
    }
    prep_weights_kernel<<<D, D, 0, stream>>>(w_gc, w_bi, wtg, wtb);

    if (ws_size >= ws_full) {
      conv_ego_kernel<<<(N_NODES * D / 4 + 255) / 256, 256, 0, stream>>>(ego, ebf);
      // Fused SpMM + transform + l2norm: no side round-trip.
      spmm_transform_kernel<<<N_NODES / 16, 256, 0, stream>>>(
          offs, ev, ebf, ego, wtg, wtb, b_gc, b_bi, out);
    } else {
      float* side = out;   // alias: spmm writes all rows; transform is row-local
      spmm_kernel<<<(N_NODES + 7) / 8, 256, 0, stream>>>(offs, ev, ego, side);
      transform_mfma_kernel<<<N_NODES / 16, 256, 0, stream>>>(
          side, ego, wtg, wtb, b_gc, b_bi, out);
    }
  } else {
    float* side = out;
    hipMemsetAsync(side, 0, (size_t)N_NODES * D * 4, stream);
    long long total = (long long)N_EDGES * 32;
    int grid = (int)((total + 255) / 256);
    scatter_kernel<<<grid, 256, 0, stream>>>(erow, ecol, eval, ego, side);
    transform_f32_kernel<<<N_NODES / 16, 128, 0, stream>>>(
        side, ego, w_gc, b_gc, w_bi, b_bi, out);
  }
}